// Round 1
// baseline (778.689 us; speedup 1.0000x reference)
//
#include <hip/hip_runtime.h>

#define N_NODES 100000
#define N_EDGES 3200000
#define F_IN 512
#define HIDDEN 16
#define N_LABELS 64

#define BW 128
#define NBUCK ((N_NODES + BW - 1) / BW)     // 782
#define NCB 256
#define SCAN_N (NBUCK * NCB)                // 200192
#define SCAN_BLKS ((SCAN_N + 1023) / 1024)  // 196
#define CAP 10240                           // LDS staging entries (40KB); buckets are 4096 +/- 64

__global__ __launch_bounds__(256) void count_kernel(
        const int* __restrict__ es, const int* __restrict__ ed,
        int* __restrict__ Msrc, int* __restrict__ Mdst) {
    __shared__ int h1[NBUCK], h2[NBUCK];
    const int tid = threadIdx.x, g = blockIdx.x;
    for (int i = tid; i < NBUCK; i += 256) { h1[i] = 0; h2[i] = 0; }
    __syncthreads();
    for (int i = g * 256 + tid; i < N_EDGES; i += NCB * 256) {
        atomicAdd(&h1[es[i] >> 7], 1);
        atomicAdd(&h2[ed[i] >> 7], 1);
    }
    __syncthreads();
    for (int i = tid; i < NBUCK; i += 256) {
        Msrc[i * NCB + g] = h1[i];
        Mdst[i * NCB + g] = h2[i];
    }
}

__global__ __launch_bounds__(256) void scanA_kernel(int* __restrict__ a, int* __restrict__ bsum) {
    __shared__ int s[256];
    const int tid = threadIdx.x;
    const int base = blockIdx.x * 1024 + tid * 4;
    int4 v = make_int4(0, 0, 0, 0);
    if (base + 3 < SCAN_N) v = *(const int4*)(a + base);
    else {
        if (base + 0 < SCAN_N) v.x = a[base + 0];
        if (base + 1 < SCAN_N) v.y = a[base + 1];
        if (base + 2 < SCAN_N) v.z = a[base + 2];
        if (base + 3 < SCAN_N) v.w = a[base + 3];
    }
    const int lsum = v.x + v.y + v.z + v.w;
    s[tid] = lsum;
    __syncthreads();
    for (int off = 1; off < 256; off <<= 1) {
        int t = (tid >= off) ? s[tid - off] : 0;
        __syncthreads();
        s[tid] += t;
        __syncthreads();
    }
    int e0 = s[tid] - lsum;
    int e1 = e0 + v.x, e2 = e1 + v.y, e3 = e2 + v.z;
    if (base + 3 < SCAN_N) *(int4*)(a + base) = make_int4(e0, e1, e2, e3);
    else {
        if (base + 0 < SCAN_N) a[base + 0] = e0;
        if (base + 1 < SCAN_N) a[base + 1] = e1;
        if (base + 2 < SCAN_N) a[base + 2] = e2;
        if (base + 3 < SCAN_N) a[base + 3] = e3;
    }
    if (tid == 255) bsum[blockIdx.x] = s[255];
}

__global__ void scanB_kernel(int* __restrict__ bsum) {
    __shared__ int s[256];
    const int tid = threadIdx.x;
    int v = (tid < SCAN_BLKS) ? bsum[tid] : 0;
    s[tid] = v;
    __syncthreads();
    for (int off = 1; off < 256; off <<= 1) {
        int t = (tid >= off) ? s[tid - off] : 0;
        __syncthreads();
        s[tid] += t;
        __syncthreads();
    }
    if (tid < SCAN_BLKS) bsum[tid] = s[tid] - v;
}

__global__ __launch_bounds__(256) void scanC_kernel(int* __restrict__ a, const int* __restrict__ bsum) {
    const int base = blockIdx.x * 1024 + threadIdx.x * 4;
    const int b = bsum[blockIdx.x];
    if (base + 3 < SCAN_N) {
        int4 v = *(int4*)(a + base);
        v.x += b; v.y += b; v.z += b; v.w += b;
        *(int4*)(a + base) = v;
    } else {
        for (int j = 0; j < 4; ++j) if (base + j < SCAN_N) a[base + j] += b;
    }
}

__global__ __launch_bounds__(256) void scatter_kernel(
        const int* __restrict__ es, const int* __restrict__ ed,
        const int* __restrict__ Ssrc, const int* __restrict__ Sdst,
        unsigned* __restrict__ pairs, unsigned char* __restrict__ srcb) {
    __shared__ int c1[NBUCK], c2[NBUCK];
    const int tid = threadIdx.x, g = blockIdx.x;
    for (int i = tid; i < NBUCK; i += 256) {
        c1[i] = Ssrc[i * NCB + g];
        c2[i] = Sdst[i * NCB + g];
    }
    __syncthreads();
    for (int i = g * 256 + tid; i < N_EDGES; i += NCB * 256) {
        int s = es[i], d = ed[i];
        int p2 = atomicAdd(&c2[d >> 7], 1);
        pairs[p2] = ((unsigned)(d & 127) << 17) | (unsigned)s;
        int p1 = atomicAdd(&c1[s >> 7], 1);
        srcb[p1] = (unsigned char)(s & 127);
    }
}

// Per-dst-bucket fine sort; converts pairs -> col IN PLACE.
__global__ __launch_bounds__(256) void csr_kernel(
        const int* __restrict__ Sdst, unsigned* __restrict__ pairs,
        int* __restrict__ row_ptr, float* __restrict__ norm_dst) {
    __shared__ unsigned buf[CAP];
    __shared__ int hist[BW], scn[BW], cur[BW];
    const int b = blockIdx.x, tid = threadIdx.x;
    const int base  = Sdst[b * NCB];
    const int nextb = (b == NBUCK - 1) ? N_EDGES : Sdst[(b + 1) * NCB];
    const int nb = nextb - base;
    const bool fits = (nb <= CAP);   // always true for this input (+96 sigma)
    if (tid < BW) hist[tid] = 0;
    __syncthreads();
    for (int i = tid; i < nb; i += 256) {
        unsigned pk = pairs[base + i];
        if (fits) buf[i] = pk;
        atomicAdd(&hist[pk >> 17], 1);
    }
    __syncthreads();
    if (tid < BW) scn[tid] = hist[tid];
    __syncthreads();
    for (int off = 1; off < BW; off <<= 1) {
        int t = 0;
        if (tid < BW && tid >= off) t = scn[tid - off];
        __syncthreads();
        if (tid < BW) scn[tid] += t;
        __syncthreads();
    }
    if (tid < BW) {
        int e = scn[tid] - hist[tid];
        cur[tid] = e;
        int node = b * BW + tid;
        if (node <= N_NODES) row_ptr[node] = base + e;
        if (node < N_NODES) norm_dst[node] = rsqrtf(fmaxf((float)hist[tid], 1.0f));
    }
    __syncthreads();
    if (fits) {
        for (int i = tid; i < nb; i += 256) {
            unsigned pk = buf[i];
            int pos = atomicAdd(&cur[pk >> 17], 1);
            pairs[base + pos] = pk & 0x1FFFFu;   // col value, within-bucket perm
        }
    } else {
        for (int i = tid; i < nb; i += 256)
            pairs[base + i] &= 0x1FFFFu;
    }
}

__global__ __launch_bounds__(256) void srcdeg_kernel(
        const int* __restrict__ Ssrc, const unsigned char* __restrict__ srcb,
        float* __restrict__ norm_src) {
    __shared__ int hist[BW];
    const int b = blockIdx.x, tid = threadIdx.x;
    const int base  = Ssrc[b * NCB];
    const int nextb = (b == NBUCK - 1) ? N_EDGES : Ssrc[(b + 1) * NCB];
    const int nb = nextb - base;
    if (tid < BW) hist[tid] = 0;
    __syncthreads();
    for (int i = tid; i < nb; i += 256)
        atomicAdd(&hist[srcb[base + i]], 1);
    __syncthreads();
    if (tid < BW) {
        int node = b * BW + tid;
        if (node < N_NODES) norm_src[node] = rsqrtf(fmaxf((float)hist[tid], 1.0f));
    }
}

#define MM_NODES 256
#define MM_CH 32
#define MM_S 257
#define KSPLIT 2
#define MM_CHUNKS ((F_IN / MM_CH) / KSPLIT)   // 8

// r5: software-pipelined (reg-prefetch) version. Old structure serialized
// [barrier -> global load -> LDS write -> barrier -> compute] per chunk, so
// HBM latency never overlapped compute within a block (only 3 blocks/CU of
// cross-block overlap -> VALUBusy 11%, 1300 GB/s). Now: loads for chunk c+1
// are issued into registers DURING compute of chunk c; the vmcnt wait lands
// at the next iteration's LDS-store, after a full compute phase.
__global__ __launch_bounds__(256, 4) void proj1_kernel(
        const float* __restrict__ X, const float* __restrict__ W1,
        float* __restrict__ P0, float* __restrict__ P1) {
    __shared__ float xsT[MM_CH][MM_S];
    __shared__ float w1c[MM_CH][HIDDEN];

    const int tid = threadIdx.x;
    const int node0 = blockIdx.x * MM_NODES;
    const int z = blockIdx.y;
    const int g  = tid >> 2;
    const int kq = (tid & 3) * 4;
    const int c0 = z * MM_CHUNKS;

    // per-thread staging addresses are loop-invariant: thread covers
    // (row r, 16B-column c4) of the 256x32 chunk.
    const int li  = tid;           // i = tid + it*256, unrolled below
    const int r0  = li >> 3;       // rows r0, r0+32, ... (8 its)
    const int c4  = li & 7;

    float acc[4][4];
#pragma unroll
    for (int a = 0; a < 4; ++a)
#pragma unroll
        for (int b = 0; b < 4; ++b) acc[a][b] = 0.f;

    float4 xp[8];
    float4 wp = make_float4(0.f, 0.f, 0.f, 0.f);

    // ---- prologue: prefetch chunk 0 into registers ----
#pragma unroll
    for (int it = 0; it < 8; ++it) {
        int r = r0 + it * 32;
        int gn = node0 + r;
        xp[it] = make_float4(0.f, 0.f, 0.f, 0.f);
        if (gn < N_NODES)
            xp[it] = *((const float4*)(X + (size_t)gn * F_IN + c0 * MM_CH + c4 * 4));
    }
    if (tid < MM_CH * HIDDEN / 4)
        wp = ((const float4*)(W1 + c0 * MM_CH * HIDDEN))[tid];

    for (int cc = 0; cc < MM_CHUNKS; ++cc) {
        __syncthreads();   // previous chunk's LDS consumers done
        // drain staged regs -> LDS (compiler inserts the vmcnt wait here,
        // a full compute phase after the loads were issued)
#pragma unroll
        for (int it = 0; it < 8; ++it) {
            int r = r0 + it * 32;
            int j = c4 * 4;
            xsT[j + 0][r] = xp[it].x;
            xsT[j + 1][r] = xp[it].y;
            xsT[j + 2][r] = xp[it].z;
            xsT[j + 3][r] = xp[it].w;
        }
        if (tid < MM_CH * HIDDEN / 4)
            ((float4*)&w1c[0][0])[tid] = wp;
        __syncthreads();

        // ---- issue next chunk's loads (no wait) ----
        if (cc + 1 < MM_CHUNKS) {
            const int c = c0 + cc + 1;
#pragma unroll
            for (int it = 0; it < 8; ++it) {
                int r = r0 + it * 32;
                int gn = node0 + r;
                xp[it] = make_float4(0.f, 0.f, 0.f, 0.f);
                if (gn < N_NODES)
                    xp[it] = *((const float4*)(X + (size_t)gn * F_IN + c * MM_CH + c4 * 4));
            }
            if (tid < MM_CH * HIDDEN / 4)
                wp = ((const float4*)(W1 + c * MM_CH * HIDDEN))[tid];
        }

        // ---- compute current chunk from LDS (overlaps in-flight loads) ----
#pragma unroll
        for (int j = 0; j < MM_CH; ++j) {
            float4 f = *((const float4*)&xsT[j][g * 4]);
            float4 w = *((const float4*)&w1c[j][kq]);
            acc[0][0] += f.x * w.x; acc[0][1] += f.x * w.y; acc[0][2] += f.x * w.z; acc[0][3] += f.x * w.w;
            acc[1][0] += f.y * w.x; acc[1][1] += f.y * w.y; acc[1][2] += f.y * w.z; acc[1][3] += f.y * w.w;
            acc[2][0] += f.z * w.x; acc[2][1] += f.z * w.y; acc[2][2] += f.z * w.z; acc[2][3] += f.z * w.w;
            acc[3][0] += f.w * w.x; acc[3][1] += f.w * w.y; acc[3][2] += f.w * w.z; acc[3][3] += f.w * w.w;
        }
    }

    float* Pz = z ? P1 : P0;
#pragma unroll
    for (int a = 0; a < 4; ++a) {
        int gn = node0 + g * 4 + a;
        if (gn < N_NODES)
            *((float4*)(Pz + (size_t)gn * HIDDEN + kq)) =
                make_float4(acc[a][0], acc[a][1], acc[a][2], acc[a][3]);
    }
}

// H1[gid] = (P0[gid]+P1[gid])*ns; H1 aliases P0 at identical element offsets
__global__ void reduce1_kernel(const float* __restrict__ P0, const float* __restrict__ P1,
                               const float* __restrict__ norm_src, float* __restrict__ H1) {
    int gid = blockIdx.x * blockDim.x + threadIdx.x;
    if (gid < N_NODES * 4) {
        float4 a = ((const float4*)P0)[gid];
        float4 b = ((const float4*)P1)[gid];
        float ns = norm_src[gid >> 2];
        ((float4*)H1)[gid] = make_float4((a.x + b.x) * ns, (a.y + b.y) * ns,
                                         (a.z + b.z) * ns, (a.w + b.w) * ns);
    }
}

__global__ __launch_bounds__(256) void spmm1_kernel(
        const int* __restrict__ rp, const int* __restrict__ col,
        const float* __restrict__ H1, const float* __restrict__ norm_dst,
        const float* __restrict__ norm_src, const float* __restrict__ b1,
        float* __restrict__ H1b) {
    int tid = threadIdx.x;
    int node = blockIdx.x * 16 + (tid >> 4);
    int k = tid & 15;
    if (node >= N_NODES) return;
    int beg = rp[node], end = rp[node + 1];
    float acc = 0.f;
    int j = beg;
    for (; j + 3 < end; j += 4) {
        int s0 = col[j], s1 = col[j + 1], s2 = col[j + 2], s3 = col[j + 3];
        float v0 = H1[(size_t)s0 * HIDDEN + k];
        float v1 = H1[(size_t)s1 * HIDDEN + k];
        float v2 = H1[(size_t)s2 * HIDDEN + k];
        float v3 = H1[(size_t)s3 * HIDDEN + k];
        acc += v0 + v1 + v2 + v3;
    }
    for (; j < end; ++j) acc += H1[(size_t)col[j] * HIDDEN + k];
    float v = fmaxf(acc * norm_dst[node] + b1[k], 0.f) * norm_src[node];
    H1b[(size_t)node * HIDDEN + k] = v;
}

__global__ __launch_bounds__(256) void spmm2_final_kernel(
        const int* __restrict__ rp, const int* __restrict__ col,
        const float* __restrict__ H1b, const float* __restrict__ norm_dst,
        const float* __restrict__ W2, const float* __restrict__ b2,
        float* __restrict__ out) {
    __shared__ float w2s[HIDDEN * N_LABELS];
    int tid = threadIdx.x;
    ((float4*)w2s)[tid] = ((const float4*)W2)[tid];
    __syncthreads();

    int node = blockIdx.x * 16 + (tid >> 4);
    int k = tid & 15;
    if (node >= N_NODES) return;
    int beg = rp[node], end = rp[node + 1];
    float acc = 0.f;
    int j = beg;
    for (; j + 3 < end; j += 4) {
        int s0 = col[j], s1 = col[j + 1], s2 = col[j + 2], s3 = col[j + 3];
        float v0 = H1b[(size_t)s0 * HIDDEN + k];
        float v1 = H1b[(size_t)s1 * HIDDEN + k];
        float v2 = H1b[(size_t)s2 * HIDDEN + k];
        float v3 = H1b[(size_t)s3 * HIDDEN + k];
        acc += v0 + v1 + v2 + v3;
    }
    for (; j < end; ++j) acc += H1b[(size_t)col[j] * HIDDEN + k];
    acc *= norm_dst[node];

    float4 o = ((const float4*)b2)[k];
#pragma unroll
    for (int jj = 0; jj < HIDDEN; ++jj) {
        float hj = __shfl(acc, jj, 16);
        float4 w = *((const float4*)&w2s[jj * N_LABELS + 4 * k]);
        o.x += hj * w.x; o.y += hj * w.y; o.z += hj * w.z; o.w += hj * w.w;
    }
    ((float4*)out)[(size_t)node * 16 + k] = o;
}

extern "C" void kernel_launch(void* const* d_in, const int* in_sizes, int n_in,
                              void* d_out, int out_size, void* d_ws, size_t ws_size,
                              hipStream_t stream) {
    const float* X  = (const float*)d_in[0];
    const float* W1 = (const float*)d_in[1];
    const float* b1 = (const float*)d_in[2];
    const float* W2 = (const float*)d_in[3];
    const float* b2 = (const float*)d_in[4];
    const int* es   = (const int*)d_in[5];
    const int* ed   = (const int*)d_in[6];
    float* out = (float*)d_out;

    // ws (~26.8MB, <= 27.6MB proven in r3): norms | row_ptr | R1 | R2 | R3
    //  R1 (6.4M): srcb (scatter..srcdeg) -> P0 (proj1..reduce1) -> H1 (..spmm1)
    //  R2 (6.4M): Sdst/Ssrc/bs (count..srcdeg) -> P1 (proj1..reduce1) -> H1b
    //  R3 (12.8M): pairs (scatter..csr, converted IN PLACE) -> col (..end)
    char* ws = (char*)d_ws;
    float* norm_src = (float*)ws;  ws += (size_t)N_NODES * 4;
    float* norm_dst = (float*)ws;  ws += (size_t)N_NODES * 4;
    int*   row_ptr  = (int*)ws;    ws += 400016;
    char*  R1 = ws;                ws += (size_t)N_NODES * HIDDEN * 4;
    char*  R2 = ws;                ws += (size_t)N_NODES * HIDDEN * 4;
    char*  R3 = ws;

    unsigned char* srcb = (unsigned char*)R1;
    float* P0  = (float*)R1;
    float* H1  = (float*)R1;
    int*   Sdst = (int*)R2;
    int*   Ssrc = (int*)(R2 + 800768);
    int*   bs1  = (int*)(R2 + 1601536);
    int*   bs2  = (int*)(R2 + 1602560);
    float* P1   = (float*)R2;
    float* H1b  = (float*)R2;
    unsigned* pairs = (unsigned*)R3;
    int*   col  = (int*)R3;

    const int NPB = (N_NODES + MM_NODES - 1) / MM_NODES;

    count_kernel<<<NCB, 256, 0, stream>>>(es, ed, Ssrc, Sdst);
    scanA_kernel<<<SCAN_BLKS, 256, 0, stream>>>(Sdst, bs1);
    scanA_kernel<<<SCAN_BLKS, 256, 0, stream>>>(Ssrc, bs2);
    scanB_kernel<<<1, 256, 0, stream>>>(bs1);
    scanB_kernel<<<1, 256, 0, stream>>>(bs2);
    scanC_kernel<<<SCAN_BLKS, 256, 0, stream>>>(Sdst, bs1);
    scanC_kernel<<<SCAN_BLKS, 256, 0, stream>>>(Ssrc, bs2);
    scatter_kernel<<<NCB, 256, 0, stream>>>(es, ed, Ssrc, Sdst, pairs, srcb);
    csr_kernel<<<NBUCK, 256, 0, stream>>>(Sdst, pairs, row_ptr, norm_dst);
    srcdeg_kernel<<<NBUCK, 256, 0, stream>>>(Ssrc, srcb, norm_src);
    proj1_kernel<<<dim3(NPB, KSPLIT), 256, 0, stream>>>(X, W1, P0, P1);
    reduce1_kernel<<<(N_NODES * 4 + 255) / 256, 256, 0, stream>>>(P0, P1, norm_src, H1);
    spmm1_kernel<<<(N_NODES + 15) / 16, 256, 0, stream>>>(row_ptr, col, H1, norm_dst, norm_src, b1, H1b);
    spmm2_final_kernel<<<(N_NODES + 15) / 16, 256, 0, stream>>>(row_ptr, col, H1b, norm_dst, W2, b2, out);
}

// Round 2
// 598.066 us; speedup vs baseline: 1.3020x; 1.3020x over previous
//
#include <hip/hip_runtime.h>

#define N_NODES 100000
#define N_EDGES 3200000
#define F_IN 512
#define HIDDEN 16
#define N_LABELS 64

#define BW 128
#define NBUCK ((N_NODES + BW - 1) / BW)     // 782
#define NCB 256
#define SCAN_N (NBUCK * NCB)                // 200192
#define SCAN_BLKS ((SCAN_N + 1023) / 1024)  // 196
#define CAP 10240                           // LDS staging entries (40KB); buckets are 4096 +/- 64

__global__ __launch_bounds__(256) void count_kernel(
        const int* __restrict__ es, const int* __restrict__ ed,
        int* __restrict__ Msrc, int* __restrict__ Mdst) {
    __shared__ int h1[NBUCK], h2[NBUCK];
    const int tid = threadIdx.x, g = blockIdx.x;
    for (int i = tid; i < NBUCK; i += 256) { h1[i] = 0; h2[i] = 0; }
    __syncthreads();
    for (int i = g * 256 + tid; i < N_EDGES; i += NCB * 256) {
        atomicAdd(&h1[es[i] >> 7], 1);
        atomicAdd(&h2[ed[i] >> 7], 1);
    }
    __syncthreads();
    for (int i = tid; i < NBUCK; i += 256) {
        Msrc[i * NCB + g] = h1[i];
        Mdst[i * NCB + g] = h2[i];
    }
}

__global__ __launch_bounds__(256) void scanA_kernel(int* __restrict__ a, int* __restrict__ bsum) {
    __shared__ int s[256];
    const int tid = threadIdx.x;
    const int base = blockIdx.x * 1024 + tid * 4;
    int4 v = make_int4(0, 0, 0, 0);
    if (base + 3 < SCAN_N) v = *(const int4*)(a + base);
    else {
        if (base + 0 < SCAN_N) v.x = a[base + 0];
        if (base + 1 < SCAN_N) v.y = a[base + 1];
        if (base + 2 < SCAN_N) v.z = a[base + 2];
        if (base + 3 < SCAN_N) v.w = a[base + 3];
    }
    const int lsum = v.x + v.y + v.z + v.w;
    s[tid] = lsum;
    __syncthreads();
    for (int off = 1; off < 256; off <<= 1) {
        int t = (tid >= off) ? s[tid - off] : 0;
        __syncthreads();
        s[tid] += t;
        __syncthreads();
    }
    int e0 = s[tid] - lsum;
    int e1 = e0 + v.x, e2 = e1 + v.y, e3 = e2 + v.z;
    if (base + 3 < SCAN_N) *(int4*)(a + base) = make_int4(e0, e1, e2, e3);
    else {
        if (base + 0 < SCAN_N) a[base + 0] = e0;
        if (base + 1 < SCAN_N) a[base + 1] = e1;
        if (base + 2 < SCAN_N) a[base + 2] = e2;
        if (base + 3 < SCAN_N) a[base + 3] = e3;
    }
    if (tid == 255) bsum[blockIdx.x] = s[255];
}

__global__ void scanB_kernel(int* __restrict__ bsum) {
    __shared__ int s[256];
    const int tid = threadIdx.x;
    int v = (tid < SCAN_BLKS) ? bsum[tid] : 0;
    s[tid] = v;
    __syncthreads();
    for (int off = 1; off < 256; off <<= 1) {
        int t = (tid >= off) ? s[tid - off] : 0;
        __syncthreads();
        s[tid] += t;
        __syncthreads();
    }
    if (tid < SCAN_BLKS) bsum[tid] = s[tid] - v;
}

__global__ __launch_bounds__(256) void scanC_kernel(int* __restrict__ a, const int* __restrict__ bsum) {
    const int base = blockIdx.x * 1024 + threadIdx.x * 4;
    const int b = bsum[blockIdx.x];
    if (base + 3 < SCAN_N) {
        int4 v = *(int4*)(a + base);
        v.x += b; v.y += b; v.z += b; v.w += b;
        *(int4*)(a + base) = v;
    } else {
        for (int j = 0; j < 4; ++j) if (base + j < SCAN_N) a[base + j] += b;
    }
}

__global__ __launch_bounds__(256) void scatter_kernel(
        const int* __restrict__ es, const int* __restrict__ ed,
        const int* __restrict__ Ssrc, const int* __restrict__ Sdst,
        unsigned* __restrict__ pairs, unsigned char* __restrict__ srcb) {
    __shared__ int c1[NBUCK], c2[NBUCK];
    const int tid = threadIdx.x, g = blockIdx.x;
    for (int i = tid; i < NBUCK; i += 256) {
        c1[i] = Ssrc[i * NCB + g];
        c2[i] = Sdst[i * NCB + g];
    }
    __syncthreads();
    for (int i = g * 256 + tid; i < N_EDGES; i += NCB * 256) {
        int s = es[i], d = ed[i];
        int p2 = atomicAdd(&c2[d >> 7], 1);
        pairs[p2] = ((unsigned)(d & 127) << 17) | (unsigned)s;
        int p1 = atomicAdd(&c1[s >> 7], 1);
        srcb[p1] = (unsigned char)(s & 127);
    }
}

// Per-dst-bucket fine sort; converts pairs -> col IN PLACE.
__global__ __launch_bounds__(256) void csr_kernel(
        const int* __restrict__ Sdst, unsigned* __restrict__ pairs,
        int* __restrict__ row_ptr, float* __restrict__ norm_dst) {
    __shared__ unsigned buf[CAP];
    __shared__ int hist[BW], scn[BW], cur[BW];
    const int b = blockIdx.x, tid = threadIdx.x;
    const int base  = Sdst[b * NCB];
    const int nextb = (b == NBUCK - 1) ? N_EDGES : Sdst[(b + 1) * NCB];
    const int nb = nextb - base;
    const bool fits = (nb <= CAP);   // always true for this input (+96 sigma)
    if (tid < BW) hist[tid] = 0;
    __syncthreads();
    for (int i = tid; i < nb; i += 256) {
        unsigned pk = pairs[base + i];
        if (fits) buf[i] = pk;
        atomicAdd(&hist[pk >> 17], 1);
    }
    __syncthreads();
    if (tid < BW) scn[tid] = hist[tid];
    __syncthreads();
    for (int off = 1; off < BW; off <<= 1) {
        int t = 0;
        if (tid < BW && tid >= off) t = scn[tid - off];
        __syncthreads();
        if (tid < BW) scn[tid] += t;
        __syncthreads();
    }
    if (tid < BW) {
        int e = scn[tid] - hist[tid];
        cur[tid] = e;
        int node = b * BW + tid;
        if (node <= N_NODES) row_ptr[node] = base + e;
        if (node < N_NODES) norm_dst[node] = rsqrtf(fmaxf((float)hist[tid], 1.0f));
    }
    __syncthreads();
    if (fits) {
        for (int i = tid; i < nb; i += 256) {
            unsigned pk = buf[i];
            int pos = atomicAdd(&cur[pk >> 17], 1);
            pairs[base + pos] = pk & 0x1FFFFu;   // col value, within-bucket perm
        }
    } else {
        for (int i = tid; i < nb; i += 256)
            pairs[base + i] &= 0x1FFFFu;
    }
}

__global__ __launch_bounds__(256) void srcdeg_kernel(
        const int* __restrict__ Ssrc, const unsigned char* __restrict__ srcb,
        float* __restrict__ norm_src) {
    __shared__ int hist[BW];
    const int b = blockIdx.x, tid = threadIdx.x;
    const int base  = Ssrc[b * NCB];
    const int nextb = (b == NBUCK - 1) ? N_EDGES : Ssrc[(b + 1) * NCB];
    const int nb = nextb - base;
    if (tid < BW) hist[tid] = 0;
    __syncthreads();
    for (int i = tid; i < nb; i += 256)
        atomicAdd(&hist[srcb[base + i]], 1);
    __syncthreads();
    if (tid < BW) {
        int node = b * BW + tid;
        if (node < N_NODES) norm_src[node] = rsqrtf(fmaxf((float)hist[tid], 1.0f));
    }
}

// r6: REVERT r5's register-staged pipeline (it spilled xp[8] to scratch:
// WRITE_SIZE 26->365MB, FETCH 135->376MB, VALUBusy 5%). Root fix for the
// latency serialization is MORE RESIDENT BLOCKS, not per-thread staging:
// MM_NODES 256->128 doubles the grid to 1564 blocks (~6/CU vs ~2.6/CU) and
// halves LDS to ~18.7KB (8 blocks/CU LDS-limit). Per-thread tile shrinks to
// 2 rows x 4 outs (acc[2][4], float2 row reads; MM_S=130 keeps 8B alignment
// and bank-conflict-free reads). Register pressure DROPS vs r4 -> no spill.
#define MM_NODES 128
#define MM_CH 32
#define MM_S 130
#define KSPLIT 2
#define MM_CHUNKS ((F_IN / MM_CH) / KSPLIT)   // 8

__global__ __launch_bounds__(256, 4) void proj1_kernel(
        const float* __restrict__ X, const float* __restrict__ W1,
        float* __restrict__ P0, float* __restrict__ P1) {
    __shared__ float xsT[MM_CH][MM_S];
    __shared__ float w1c[MM_CH][HIDDEN];

    const int tid = threadIdx.x;
    const int node0 = blockIdx.x * MM_NODES;
    const int z = blockIdx.y;
    const int g  = tid >> 2;              // 0..63 -> rows g*2, g*2+1
    const int kq = (tid & 3) * 4;
    const int c0 = z * MM_CHUNKS;

    float acc[2][4];
#pragma unroll
    for (int a = 0; a < 2; ++a)
#pragma unroll
        for (int b = 0; b < 4; ++b) acc[a][b] = 0.f;

    for (int cc = 0; cc < MM_CHUNKS; ++cc) {
        const int c = c0 + cc;
        __syncthreads();
        if (tid < MM_CH * HIDDEN / 4)
            ((float4*)&w1c[0][0])[tid] = ((const float4*)(W1 + c * MM_CH * HIDDEN))[tid];
        // stage 128 rows x 32 cols: 1024 float4, 4 per thread
#pragma unroll
        for (int it = 0; it < 4; ++it) {
            int i  = tid + it * 256;
            int r  = i >> 3;
            int c4 = i & 7;
            float4 v = make_float4(0.f, 0.f, 0.f, 0.f);
            int gn = node0 + r;
            if (gn < N_NODES)
                v = *((const float4*)(X + (size_t)gn * F_IN + c * MM_CH + c4 * 4));
            int j = c4 * 4;
            xsT[j + 0][r] = v.x;
            xsT[j + 1][r] = v.y;
            xsT[j + 2][r] = v.z;
            xsT[j + 3][r] = v.w;
        }
        __syncthreads();
#pragma unroll
        for (int j = 0; j < MM_CH; ++j) {
            float2 f = *((const float2*)&xsT[j][g * 2]);
            float4 w = *((const float4*)&w1c[j][kq]);
            acc[0][0] += f.x * w.x; acc[0][1] += f.x * w.y; acc[0][2] += f.x * w.z; acc[0][3] += f.x * w.w;
            acc[1][0] += f.y * w.x; acc[1][1] += f.y * w.y; acc[1][2] += f.y * w.z; acc[1][3] += f.y * w.w;
        }
    }

    float* Pz = z ? P1 : P0;
#pragma unroll
    for (int a = 0; a < 2; ++a) {
        int gn = node0 + g * 2 + a;
        if (gn < N_NODES)
            *((float4*)(Pz + (size_t)gn * HIDDEN + kq)) =
                make_float4(acc[a][0], acc[a][1], acc[a][2], acc[a][3]);
    }
}

// H1[gid] = (P0[gid]+P1[gid])*ns; H1 aliases P0 at identical element offsets
__global__ void reduce1_kernel(const float* __restrict__ P0, const float* __restrict__ P1,
                               const float* __restrict__ norm_src, float* __restrict__ H1) {
    int gid = blockIdx.x * blockDim.x + threadIdx.x;
    if (gid < N_NODES * 4) {
        float4 a = ((const float4*)P0)[gid];
        float4 b = ((const float4*)P1)[gid];
        float ns = norm_src[gid >> 2];
        ((float4*)H1)[gid] = make_float4((a.x + b.x) * ns, (a.y + b.y) * ns,
                                         (a.z + b.z) * ns, (a.w + b.w) * ns);
    }
}

__global__ __launch_bounds__(256) void spmm1_kernel(
        const int* __restrict__ rp, const int* __restrict__ col,
        const float* __restrict__ H1, const float* __restrict__ norm_dst,
        const float* __restrict__ norm_src, const float* __restrict__ b1,
        float* __restrict__ H1b) {
    int tid = threadIdx.x;
    int node = blockIdx.x * 16 + (tid >> 4);
    int k = tid & 15;
    if (node >= N_NODES) return;
    int beg = rp[node], end = rp[node + 1];
    float acc = 0.f;
    int j = beg;
    for (; j + 3 < end; j += 4) {
        int s0 = col[j], s1 = col[j + 1], s2 = col[j + 2], s3 = col[j + 3];
        float v0 = H1[(size_t)s0 * HIDDEN + k];
        float v1 = H1[(size_t)s1 * HIDDEN + k];
        float v2 = H1[(size_t)s2 * HIDDEN + k];
        float v3 = H1[(size_t)s3 * HIDDEN + k];
        acc += v0 + v1 + v2 + v3;
    }
    for (; j < end; ++j) acc += H1[(size_t)col[j] * HIDDEN + k];
    float v = fmaxf(acc * norm_dst[node] + b1[k], 0.f) * norm_src[node];
    H1b[(size_t)node * HIDDEN + k] = v;
}

__global__ __launch_bounds__(256) void spmm2_final_kernel(
        const int* __restrict__ rp, const int* __restrict__ col,
        const float* __restrict__ H1b, const float* __restrict__ norm_dst,
        const float* __restrict__ W2, const float* __restrict__ b2,
        float* __restrict__ out) {
    __shared__ float w2s[HIDDEN * N_LABELS];
    int tid = threadIdx.x;
    ((float4*)w2s)[tid] = ((const float4*)W2)[tid];
    __syncthreads();

    int node = blockIdx.x * 16 + (tid >> 4);
    int k = tid & 15;
    if (node >= N_NODES) return;
    int beg = rp[node], end = rp[node + 1];
    float acc = 0.f;
    int j = beg;
    for (; j + 3 < end; j += 4) {
        int s0 = col[j], s1 = col[j + 1], s2 = col[j + 2], s3 = col[j + 3];
        float v0 = H1b[(size_t)s0 * HIDDEN + k];
        float v1 = H1b[(size_t)s1 * HIDDEN + k];
        float v2 = H1b[(size_t)s2 * HIDDEN + k];
        float v3 = H1b[(size_t)s3 * HIDDEN + k];
        acc += v0 + v1 + v2 + v3;
    }
    for (; j < end; ++j) acc += H1b[(size_t)col[j] * HIDDEN + k];
    acc *= norm_dst[node];

    float4 o = ((const float4*)b2)[k];
#pragma unroll
    for (int jj = 0; jj < HIDDEN; ++jj) {
        float hj = __shfl(acc, jj, 16);
        float4 w = *((const float4*)&w2s[jj * N_LABELS + 4 * k]);
        o.x += hj * w.x; o.y += hj * w.y; o.z += hj * w.z; o.w += hj * w.w;
    }
    ((float4*)out)[(size_t)node * 16 + k] = o;
}

extern "C" void kernel_launch(void* const* d_in, const int* in_sizes, int n_in,
                              void* d_out, int out_size, void* d_ws, size_t ws_size,
                              hipStream_t stream) {
    const float* X  = (const float*)d_in[0];
    const float* W1 = (const float*)d_in[1];
    const float* b1 = (const float*)d_in[2];
    const float* W2 = (const float*)d_in[3];
    const float* b2 = (const float*)d_in[4];
    const int* es   = (const int*)d_in[5];
    const int* ed   = (const int*)d_in[6];
    float* out = (float*)d_out;

    // ws (~26.8MB, <= 27.6MB proven in r3): norms | row_ptr | R1 | R2 | R3
    //  R1 (6.4M): srcb (scatter..srcdeg) -> P0 (proj1..reduce1) -> H1 (..spmm1)
    //  R2 (6.4M): Sdst/Ssrc/bs (count..srcdeg) -> P1 (proj1..reduce1) -> H1b
    //  R3 (12.8M): pairs (scatter..csr, converted IN PLACE) -> col (..end)
    char* ws = (char*)d_ws;
    float* norm_src = (float*)ws;  ws += (size_t)N_NODES * 4;
    float* norm_dst = (float*)ws;  ws += (size_t)N_NODES * 4;
    int*   row_ptr  = (int*)ws;    ws += 400016;
    char*  R1 = ws;                ws += (size_t)N_NODES * HIDDEN * 4;
    char*  R2 = ws;                ws += (size_t)N_NODES * HIDDEN * 4;
    char*  R3 = ws;

    unsigned char* srcb = (unsigned char*)R1;
    float* P0  = (float*)R1;
    float* H1  = (float*)R1;
    int*   Sdst = (int*)R2;
    int*   Ssrc = (int*)(R2 + 800768);
    int*   bs1  = (int*)(R2 + 1601536);
    int*   bs2  = (int*)(R2 + 1602560);
    float* P1   = (float*)R2;
    float* H1b  = (float*)R2;
    unsigned* pairs = (unsigned*)R3;
    int*   col  = (int*)R3;

    const int NPB = (N_NODES + MM_NODES - 1) / MM_NODES;  // 782

    count_kernel<<<NCB, 256, 0, stream>>>(es, ed, Ssrc, Sdst);
    scanA_kernel<<<SCAN_BLKS, 256, 0, stream>>>(Sdst, bs1);
    scanA_kernel<<<SCAN_BLKS, 256, 0, stream>>>(Ssrc, bs2);
    scanB_kernel<<<1, 256, 0, stream>>>(bs1);
    scanB_kernel<<<1, 256, 0, stream>>>(bs2);
    scanC_kernel<<<SCAN_BLKS, 256, 0, stream>>>(Sdst, bs1);
    scanC_kernel<<<SCAN_BLKS, 256, 0, stream>>>(Ssrc, bs2);
    scatter_kernel<<<NCB, 256, 0, stream>>>(es, ed, Ssrc, Sdst, pairs, srcb);
    csr_kernel<<<NBUCK, 256, 0, stream>>>(Sdst, pairs, row_ptr, norm_dst);
    srcdeg_kernel<<<NBUCK, 256, 0, stream>>>(Ssrc, srcb, norm_src);
    proj1_kernel<<<dim3(NPB, KSPLIT), 256, 0, stream>>>(X, W1, P0, P1);
    reduce1_kernel<<<(N_NODES * 4 + 255) / 256, 256, 0, stream>>>(P0, P1, norm_src, H1);
    spmm1_kernel<<<(N_NODES + 15) / 16, 256, 0, stream>>>(row_ptr, col, H1, norm_dst, norm_src, b1, H1b);
    spmm2_final_kernel<<<(N_NODES + 15) / 16, 256, 0, stream>>>(row_ptr, col, H1b, norm_dst, W2, b2, out);
}